// Round 10
// baseline (272.220 us; speedup 1.0000x reference)
//
#include <hip/hip_runtime.h>
#include <hip/hip_bf16.h>

// EvenOddFunctionHAM: out = rho(rho(s)@W + b_odd + [Ux|0]) @ W^T + b_even
// R9 -> R10: cross-block de-phasing. 8-wave blocks (512 thr), BM=256 BN=128
// BK=32, LDS 72KB (3-deep A+B) => 2 blocks/CU co-resident, still 4
// waves/SIMD (VGPR ~96). De-phased blocks hide each other's barrier/lgkm
// stalls; heavy-first ordering pairs 1 heavy + 1 light block per CU.
// Swizzle for 64B rows: slot = fq ^ ((fr>>1)&3) (2-way bank alias = free).
// setprio removed (m190: hurts lockstep GEMM).

#define N_DIM 4096
#define D1_DIM 2048

typedef short short8 __attribute__((ext_vector_type(8)));
typedef float f32x4 __attribute__((ext_vector_type(4)));

__device__ __forceinline__ float rho_f(float x) {
    return 1.0f / (1.0f + __expf(2.0f - 4.0f * x));  // sigmoid(4x-2)
}

__device__ __forceinline__ unsigned short f2bf(float x) {
    unsigned int u = __builtin_bit_cast(unsigned int, x);
    u += 0x7fffu + ((u >> 16) & 1u);
    return (unsigned short)(u >> 16);
}

__device__ __forceinline__ void gl_lds16(const unsigned short* g, void* l) {
    __builtin_amdgcn_global_load_lds(
        (const __attribute__((address_space(1))) void*)g,
        (__attribute__((address_space(3))) void*)l, 16, 0, 0);
}

// ---------------- merged prep (unchanged from R8) ----------------
__global__ __launch_bounds__(256) void prep_kernel(
    const float* __restrict__ s, const float* __restrict__ W,
    unsigned short* __restrict__ Rs, unsigned short* __restrict__ Wb,
    unsigned short* __restrict__ WTb) {
    __shared__ unsigned short t[32][33];
    const int id = blockIdx.x;
    if (id < 16384) {
        const int bx = id & 127, by = id >> 7;
        if (by * 32 >= D1_DIM && bx * 32 < D1_DIM) return;  // dead block
        const int tx = threadIdx.x & 31, ty = threadIdx.x >> 5;  // 32 x 8
        const int x = bx * 32 + tx;
        #pragma unroll
        for (int r = 0; r < 4; r++) {
            const int y = by * 32 + ty + r * 8;
            const size_t idx = (size_t)y * N_DIM + x;
            const unsigned short b = f2bf(W[idx]);
            Wb[idx] = b;
            t[ty + r * 8][tx] = b;
        }
        __syncthreads();
        #pragma unroll
        for (int r = 0; r < 4; r++) {
            const int yy = ty + r * 8;
            WTb[(size_t)(bx * 32 + yy) * N_DIM + (by * 32 + tx)] = t[tx][yy];
        }
    } else {
        const int n8 = (N_DIM * N_DIM) / 8;
        const int stride = 2048 * 256;
        for (int i = (id - 16384) * 256 + threadIdx.x; i < n8; i += stride) {
            float4 a = ((const float4*)s)[2 * i];
            float4 b = ((const float4*)s)[2 * i + 1];
            unsigned int r0 = f2bf(rho_f(a.x)) | ((unsigned int)f2bf(rho_f(a.y)) << 16);
            unsigned int r1 = f2bf(rho_f(a.z)) | ((unsigned int)f2bf(rho_f(a.w)) << 16);
            unsigned int r2 = f2bf(rho_f(b.x)) | ((unsigned int)f2bf(rho_f(b.y)) << 16);
            unsigned int r3 = f2bf(rho_f(b.z)) | ((unsigned int)f2bf(rho_f(b.w)) << 16);
            uint4 o; o.x = r0; o.y = r1; o.z = r2; o.w = r3;
            ((uint4*)Rs)[i] = o;
        }
    }
}

// ---------------- GEMM 256x128, BK=32, 8 waves (4Mx2N), 2 blocks/CU ------
// C = A @ Bt^T. A[M][K], Bt[N][K] bf16 row-major (ld=4096), fp32 acc.
// LDS (72KB): A bufs 16KB at 0/16K/32K; B bufs 8KB at 48K/56K/64K.
// Tile t reads buf t%3; stages t+2 -> buf (t+2)%3. vmcnt(3) per tile
// drains exactly tile t+1's 3 loads (FIFO). One barrier per tile.
// Row = 64B = 4 chunks; LDS slot s of row R holds global chunk s^((R>>1)&3)
// (source-side on gl_lds, read-side on ds_read; 2-way bank alias = free).
template<int MODE>
__global__ __launch_bounds__(512, 4) void gemm_kernel(
    const unsigned short* __restrict__ A,
    const unsigned short* __restrict__ Bt,
    void* __restrict__ Out,
    const float* __restrict__ Ux,
    const float* __restrict__ bias) {
    __shared__ __align__(16) char lds[73728];

    // heavy-first (ids 0..255 = full-K blocks) + XCD remap within group
    const int id = blockIdx.x;
    const int grp = id >> 8;                       // 0 = heavy, 1 = light
    const int i = id & 255;
    const int tile = ((i & 7) << 5) | (i >> 3);    // XCD x -> rows {2x,2x+1}
    const int by = tile >> 4;
    const int bxg = tile & 15;
    int bx;
    if (MODE == 1) bx = grp ? bxg : 16 + bxg;      // heavy: bcol >= 2048
    else           bx = grp ? 16 + bxg : bxg;      // heavy: bcol < 2048
    const int brow = by << 8;
    const int bcol = bx << 7;

    const int tid = threadIdx.x;
    const int w = tid >> 6;        // wave 0..7
    const int L = tid & 63;
    const int wr = w >> 1;         // 0..3 : rows wr*64..+63
    const int wc = w & 1;          // 0..1 : cols wc*64..+63
    const int fr = L & 15;
    const int fq = L >> 4;         // 0..3

    // block-sparse K range (exact: skipped W blocks are all-zero)
    int kbeg, kend;
    if (MODE == 1) { kbeg = 0; kend = (bcol < D1_DIM) ? D1_DIM : N_DIM; }
    else           { kbeg = (bcol < D1_DIM) ? 0 : D1_DIM; kend = N_DIM; }

    // ---- staging geometry: thread -> (row = tid>>2, slot = tid&3) ----
    const int srow = tid >> 2;                     // 0..127
    const int schunk = (tid & 3) ^ ((srow >> 1) & 3);
    const unsigned short* gA0 = A + (size_t)(brow + srow) * N_DIM + schunk * 8;
    const unsigned short* gA1 = gA0 + 128 * N_DIM; // rows 128..255 (same chunk)
    const unsigned short* gB0 = Bt + (size_t)(bcol + srow) * N_DIM + schunk * 8;
    const int dst16 = tid * 16;
    // stage tile kt into buf index bi (A: 2 loads, B: 1 load per thread)
#define STAGE(kcol, bi) do {                                                   \
        gl_lds16(gA0 + (kcol), lds + (bi) * 16384 + dst16);                    \
        gl_lds16(gA1 + (kcol), lds + (bi) * 16384 + 8192 + dst16);             \
        gl_lds16(gB0 + (kcol), lds + 49152 + (bi) * 8192 + dst16);             \
    } while (0)

    // ---- fragment reads: slot = fq ^ ((fr>>1)&3), same for every frag ----
    const int slotb = (fq ^ ((fr >> 1) & 3)) << 4;
    short8 af[4], bf[4];
#define LDFRAGS(bi) do {                                                       \
        const char* ab_ = lds + (bi) * 16384;                                  \
        const char* bb_ = lds + 49152 + (bi) * 8192;                           \
        _Pragma("unroll") for (int m_ = 0; m_ < 4; ++m_)                       \
            af[m_] = *(const short8*)(ab_ + (wr * 64 + m_ * 16 + fr) * 64 +    \
                                      slotb);                                  \
        _Pragma("unroll") for (int n_ = 0; n_ < 4; ++n_)                       \
            bf[n_] = *(const short8*)(bb_ + (wc * 64 + n_ * 16 + fr) * 64 +    \
                                      slotb);                                  \
    } while (0)

    f32x4 acc[4][4];
    #pragma unroll
    for (int m = 0; m < 4; m++)
        #pragma unroll
        for (int n = 0; n < 4; n++)
            acc[m][n] = (f32x4){0.f, 0.f, 0.f, 0.f};

#define SBAR0() __builtin_amdgcn_sched_barrier(0)
#define BAR() __builtin_amdgcn_s_barrier()

    const int nk = (kend - kbeg) >> 5;   // 64 or 128
    const int km = nk - 1;

    // ---- prologue: stage t0, t1 (6 loads FIFO); vmcnt(3) -> t0 ready
    STAGE(kbeg, 0);
    STAGE(kbeg + ((1 & km) << 5), 1);
    asm volatile("s_waitcnt vmcnt(3)" ::: "memory");
    BAR();

    int ci = 0, si = 2;                  // buf[t%3], buf[(t+2)%3]
    for (int t = 0; t < nk; ++t) {
        const int ka = kbeg + (((t + 2) & km) << 5);   // wrapped tail: dead
        // stage t+2 -> buf[(t+2)%3] (slot read at t-1, freed by its barrier)
        STAGE(ka, si);
        // 8 ds_reads for tile t
        LDFRAGS(ci);
        asm volatile("s_waitcnt lgkmcnt(0)" ::: "memory");
        SBAR0();
        #pragma unroll
        for (int m = 0; m < 4; ++m)
            #pragma unroll
            for (int n = 0; n < 4; ++n)
                acc[m][n] = __builtin_amdgcn_mfma_f32_16x16x32_bf16(
                    af[m], bf[n], acc[m][n], 0, 0, 0);
        // drain exactly tile t+1's 3 loads (FIFO), keep t+2's 3 in flight
        asm volatile("s_waitcnt vmcnt(3)" ::: "memory");
        BAR();
        ci++; if (ci == 3) ci = 0;
        si++; if (si == 3) si = 0;
    }
    // drain dead tail stages before block exit (LDS reuse by next block)
    asm volatile("s_waitcnt vmcnt(0)" ::: "memory");

    // ---- epilogue: C/D layout col = fr (N), row = fq*4 + reg (M) ----
    const bool hasUx = (MODE == 1) && (bcol < D1_DIM);
    #pragma unroll
    for (int m = 0; m < 4; m++) {
        const int row0 = brow + wr * 64 + m * 16 + fq * 4;
        #pragma unroll
        for (int n = 0; n < 4; n++) {
            const int col = bcol + wc * 64 + n * 16 + fr;
            const float bv = bias[col];
            #pragma unroll
            for (int r = 0; r < 4; r++) {
                const int row = row0 + r;
                float v = acc[m][n][r] + bv;
                if (MODE == 1) {
                    if (hasUx) v += Ux[(size_t)row * D1_DIM + col];
                    ((unsigned short*)Out)[(size_t)row * N_DIM + col] =
                        f2bf(rho_f(v));
                } else {
                    ((float*)Out)[(size_t)row * N_DIM + col] = v;
                }
            }
        }
    }
#undef STAGE
#undef LDFRAGS
#undef SBAR0
#undef BAR
}

extern "C" void kernel_launch(void* const* d_in, const int* in_sizes, int n_in,
                              void* d_out, int out_size, void* d_ws, size_t ws_size,
                              hipStream_t stream) {
    const float* Ux     = (const float*)d_in[0];  // [4096][2048]
    const float* s      = (const float*)d_in[1];  // [4096][4096]
    const float* W      = (const float*)d_in[2];  // [4096][4096]
    const float* b_even = (const float*)d_in[3];  // [4096]
    const float* b_odd  = (const float*)d_in[4];  // [4096]
    // d_in[5] = W_mask: unused (masked block is never read)

    char* ws = (char*)d_ws;
    const size_t SZ = (size_t)N_DIM * N_DIM * 2;  // 32 MB per bf16 matrix
    unsigned short* Rs  = (unsigned short*)(ws);
    unsigned short* R2  = (unsigned short*)(ws + SZ);
    unsigned short* Wb  = (unsigned short*)(ws + 2 * SZ);
    unsigned short* WTb = (unsigned short*)(ws + 3 * SZ);

    // merged prep: 16384 W-tile blocks + 2048 rho(s) blocks
    prep_kernel<<<18432, 256, 0, stream>>>(s, W, Rs, Wb, WTb);
    // GEMM1: s_odd = Rs @ W  (+b_odd, +Ux, rho) -> R2 bf16
    gemm_kernel<1><<<512, 512, 0, stream>>>(Rs, WTb, (void*)R2, Ux, b_odd);
    // GEMM2: out = R2 @ W^T (+b_even) -> d_out f32
    gemm_kernel<2><<<512, 512, 0, stream>>>(R2, Wb, d_out, Ux, b_even);
}

// Round 11
// 241.981 us; speedup vs baseline: 1.1250x; 1.1250x over previous
//
#include <hip/hip_runtime.h>
#include <hip/hip_bf16.h>

// EvenOddFunctionHAM: out = rho(rho(s)@W + b_odd + [Ux|0]) @ W^T + b_even
// R10 -> R11: revert to R9 (best, 248.5us); single change: ONE barrier per
// K-tile. B(t+2) staging moves after the tile-end barrier (its slot's
// readers are past the BAR), killing R9's BAR#1. Counted vmcnt(2)/tile:
// steady-state FIFO at the wait = [A(t+1),B(t+1),A(t+2)] -> drain exactly
// t+1's 4 loads, keep A(t+2) in flight. Prologue vmcnt(4).

#define N_DIM 4096
#define D1_DIM 2048

typedef short short8 __attribute__((ext_vector_type(8)));
typedef float f32x4 __attribute__((ext_vector_type(4)));

__device__ __forceinline__ float rho_f(float x) {
    return 1.0f / (1.0f + __expf(2.0f - 4.0f * x));  // sigmoid(4x-2)
}

__device__ __forceinline__ unsigned short f2bf(float x) {
    unsigned int u = __builtin_bit_cast(unsigned int, x);
    u += 0x7fffu + ((u >> 16) & 1u);
    return (unsigned short)(u >> 16);
}

__device__ __forceinline__ void gl_lds16(const unsigned short* g, void* l) {
    __builtin_amdgcn_global_load_lds(
        (const __attribute__((address_space(1))) void*)g,
        (__attribute__((address_space(3))) void*)l, 16, 0, 0);
}

// ---------------- merged prep (unchanged from R8) ----------------
__global__ __launch_bounds__(256) void prep_kernel(
    const float* __restrict__ s, const float* __restrict__ W,
    unsigned short* __restrict__ Rs, unsigned short* __restrict__ Wb,
    unsigned short* __restrict__ WTb) {
    __shared__ unsigned short t[32][33];
    const int id = blockIdx.x;
    if (id < 16384) {
        const int bx = id & 127, by = id >> 7;
        if (by * 32 >= D1_DIM && bx * 32 < D1_DIM) return;  // dead block
        const int tx = threadIdx.x & 31, ty = threadIdx.x >> 5;  // 32 x 8
        const int x = bx * 32 + tx;
        #pragma unroll
        for (int r = 0; r < 4; r++) {
            const int y = by * 32 + ty + r * 8;
            const size_t idx = (size_t)y * N_DIM + x;
            const unsigned short b = f2bf(W[idx]);
            Wb[idx] = b;
            t[ty + r * 8][tx] = b;
        }
        __syncthreads();
        #pragma unroll
        for (int r = 0; r < 4; r++) {
            const int yy = ty + r * 8;
            WTb[(size_t)(bx * 32 + yy) * N_DIM + (by * 32 + tx)] = t[tx][yy];
        }
    } else {
        const int n8 = (N_DIM * N_DIM) / 8;
        const int stride = 2048 * 256;
        for (int i = (id - 16384) * 256 + threadIdx.x; i < n8; i += stride) {
            float4 a = ((const float4*)s)[2 * i];
            float4 b = ((const float4*)s)[2 * i + 1];
            unsigned int r0 = f2bf(rho_f(a.x)) | ((unsigned int)f2bf(rho_f(a.y)) << 16);
            unsigned int r1 = f2bf(rho_f(a.z)) | ((unsigned int)f2bf(rho_f(a.w)) << 16);
            unsigned int r2 = f2bf(rho_f(b.x)) | ((unsigned int)f2bf(rho_f(b.y)) << 16);
            unsigned int r3 = f2bf(rho_f(b.z)) | ((unsigned int)f2bf(rho_f(b.w)) << 16);
            uint4 o; o.x = r0; o.y = r1; o.z = r2; o.w = r3;
            ((uint4*)Rs)[i] = o;
        }
    }
}

// ---------------- GEMM 256x256, BK=64, 16 waves (4x4), 1 barrier/tile ----
// C = A @ Bt^T. A[M][K], Bt[N][K] bf16 row-major (ld=4096), fp32 acc.
// LDS: A bufs 0/32K/64K (tile t reads a[t%3]; A(t+2)->a[(t+2)%3] at tile
// top); B bufs 96K/128K (tile t reads b[t%2]; B(t+2)->b[t%2] AFTER the
// tile barrier — readers of that slot are past it). vmcnt(2) before BAR
// drains exactly tile t+1's A+B (FIFO), leaves A(t+2) in flight.
// Swizzle: LDS[r][chunk c] = G[r][c ^ (r&7)], source-side + read-side.
template<int MODE>
__global__ __launch_bounds__(1024, 4) void gemm_kernel(
    const unsigned short* __restrict__ A,
    const unsigned short* __restrict__ Bt,
    void* __restrict__ Out,
    const float* __restrict__ Ux,
    const float* __restrict__ bias) {
    __shared__ __align__(16) char lds[163840];

    // XCD remap: XCD x gets tile-rows {2x, 2x+1}
    const int id = blockIdx.x;
    const int wg = ((id & 7) << 5) | (id >> 3);
    const int by = wg >> 4, bx = wg & 15;
    const int brow = by << 8, bcol = bx << 8;

    const int tid = threadIdx.x;
    const int w = tid >> 6;        // wave 0..15
    const int L = tid & 63;
    const int wr = w >> 2;         // 0..3 : rows wr*64..+63
    const int wc = w & 3;          // 0..3 : cols wc*64..+63
    const int fr = L & 15;
    const int fq = L >> 4;
    const int swz = fr & 7;

    // block-sparse K range (exact: skipped W blocks are all-zero)
    int kbeg, kend;
    if (MODE == 1) { kbeg = 0; kend = (bcol < D1_DIM) ? D1_DIM : N_DIM; }
    else           { kbeg = (bcol < D1_DIM) ? 0 : D1_DIM; kend = N_DIM; }

    // staging: one gl_lds16/thread = 128 rows x 64 cols (16KB); full 256-row
    // matrix tile = 2 instrs. wave w covers rows w*8+(L>>3) (+128 for h=1).
    const int srl = w * 8 + (L >> 3);
    const int schunk8 = ((L & 7) ^ (L >> 3)) << 3;
    const int wbase = w * 1024;
#define STAGEF(mat, gb, kcol, base) do {                                       \
        const unsigned short* g0_ = (mat) +                                    \
            (size_t)((gb) + srl) * N_DIM + (kcol) + schunk8;                   \
        gl_lds16(g0_, lds + (base) + wbase);                                   \
        gl_lds16(g0_ + 128 * N_DIM, lds + (base) + 16384 + wbase);             \
    } while (0)

    short8 af[2][4], bf[4];
#define LDA_K(ab, ks) do {                                                     \
        _Pragma("unroll") for (int m_ = 0; m_ < 4; ++m_) {                     \
            const int R_ = wr * 64 + m_ * 16 + fr;                             \
            af[ks][m_] = *(const short8*)(lds + (ab) + R_ * 128 +              \
                ((((ks) * 4 + fq) ^ swz) << 4)); }                             \
    } while (0)
#define LDB_K(bb, ks) do {                                                     \
        _Pragma("unroll") for (int n_ = 0; n_ < 4; ++n_) {                     \
            const int R_ = wc * 64 + n_ * 16 + fr;                             \
            bf[n_] = *(const short8*)(lds + (bb) + R_ * 128 +                  \
                ((((ks) * 4 + fq) ^ swz) << 4)); }                             \
    } while (0)

    f32x4 acc[4][4];
    #pragma unroll
    for (int i = 0; i < 4; i++)
        #pragma unroll
        for (int j = 0; j < 4; j++)
            acc[i][j] = (f32x4){0.f, 0.f, 0.f, 0.f};

#define MFMA_K(ks) do {                                                        \
        __builtin_amdgcn_s_setprio(1);                                         \
        _Pragma("unroll") for (int m_ = 0; m_ < 4; ++m_)                       \
        _Pragma("unroll") for (int n_ = 0; n_ < 4; ++n_)                       \
            acc[m_][n_] = __builtin_amdgcn_mfma_f32_16x16x32_bf16(             \
                af[ks][m_], bf[n_], acc[m_][n_], 0, 0, 0);                     \
        __builtin_amdgcn_s_setprio(0);                                         \
    } while (0)

#define SBAR0() __builtin_amdgcn_sched_barrier(0)
#define LGKM(n) do { asm volatile("s_waitcnt lgkmcnt(" #n ")" ::: "memory");   \
                     SBAR0(); } while (0)
#define BAR() __builtin_amdgcn_s_barrier()

    const int nk = (kend - kbeg) >> 6;   // 32 or 64
    const int km = nk - 1;

    // ---- prologue: A(0),B(0),A(1),B(1) (8 loads FIFO); vmcnt(4): t0 ready
    {
        const int k0 = kbeg;
        const int k1 = kbeg + ((1 & km) << 6);
        STAGEF(A, brow, k0, 0);       STAGEF(Bt, bcol, k0, 98304);
        STAGEF(A, brow, k1, 32768);   STAGEF(Bt, bcol, k1, 131072);
        asm volatile("s_waitcnt vmcnt(4)" ::: "memory");
        BAR();
    }

    int ai = 0, si = 2;                   // a[t%3], a[(t+2)%3]
    for (int t = 0; t < nk; ++t) {
        const int aB = ai * 32768;
        const int sA = si * 32768;
        const int bB = 98304 + (t & 1) * 32768;
        const int ka = kbeg + (((t + 2) & km) << 6);   // wrapped tail: dead

        // top: stage A(t+2) -> a[(t+2)%3] (slot read at t-1, post-barrier)
        STAGEF(A, brow, ka, sA);
        // reads: A0(4), B0(4), A1(4) up-front
        LDA_K(aB, 0); SBAR0();
        LDB_K(bB, 0); SBAR0();
        LDA_K(aB, 1); SBAR0();
        LGKM(4);                       // A0+B0 landed (A1 may be in flight)
        MFMA_K(0);
        LDB_K(bB, 1); SBAR0();         // re-read bf for ks1 (WAR-safe)
        LGKM(0);                       // +A1,B1 landed
        MFMA_K(1);
        // drain exactly tile t+1's 4 loads (FIFO: A(t+1),B(t+1) oldest),
        // keep A(t+2)'s 2 in flight
        asm volatile("s_waitcnt vmcnt(2)" ::: "memory");
        BAR();                         // single tile barrier
        // bottom: stage B(t+2) -> b[t%2] (readers of this slot passed BAR)
        STAGEF(Bt, bcol, ka, bB);
        ai++; if (ai == 3) ai = 0;
        si++; if (si == 3) si = 0;
    }
    // drain dead tail stages: must not land in the NEXT block's LDS
    asm volatile("s_waitcnt vmcnt(0)" ::: "memory");

    // ---- epilogue: C/D layout col = fr (N), row = fq*4 + reg (M) ----
    const bool hasUx = (MODE == 1) && (bcol < D1_DIM);
    #pragma unroll
    for (int m = 0; m < 4; m++) {
        const int row0 = brow + wr * 64 + m * 16 + fq * 4;
        #pragma unroll
        for (int n = 0; n < 4; n++) {
            const int col = bcol + wc * 64 + n * 16 + fr;
            const float bv = bias[col];
            #pragma unroll
            for (int r = 0; r < 4; r++) {
                const int row = row0 + r;
                float v = acc[m][n][r] + bv;
                if (MODE == 1) {
                    if (hasUx) v += Ux[(size_t)row * D1_DIM + col];
                    ((unsigned short*)Out)[(size_t)row * N_DIM + col] =
                        f2bf(rho_f(v));
                } else {
                    ((float*)Out)[(size_t)row * N_DIM + col] = v;
                }
            }
        }
    }
#undef STAGEF
#undef LDA_K
#undef LDB_K
#undef MFMA_K
#undef SBAR0
#undef LGKM
#undef BAR
}

extern "C" void kernel_launch(void* const* d_in, const int* in_sizes, int n_in,
                              void* d_out, int out_size, void* d_ws, size_t ws_size,
                              hipStream_t stream) {
    const float* Ux     = (const float*)d_in[0];  // [4096][2048]
    const float* s      = (const float*)d_in[1];  // [4096][4096]
    const float* W      = (const float*)d_in[2];  // [4096][4096]
    const float* b_even = (const float*)d_in[3];  // [4096]
    const float* b_odd  = (const float*)d_in[4];  // [4096]
    // d_in[5] = W_mask: unused (masked block is never read)

    char* ws = (char*)d_ws;
    const size_t SZ = (size_t)N_DIM * N_DIM * 2;  // 32 MB per bf16 matrix
    unsigned short* Rs  = (unsigned short*)(ws);
    unsigned short* R2  = (unsigned short*)(ws + SZ);
    unsigned short* Wb  = (unsigned short*)(ws + 2 * SZ);
    unsigned short* WTb = (unsigned short*)(ws + 3 * SZ);

    // merged prep: 16384 W-tile blocks + 2048 rho(s) blocks
    prep_kernel<<<18432, 256, 0, stream>>>(s, W, Rs, Wb, WTb);
    // GEMM1: s_odd = Rs @ W  (+b_odd, +Ux, rho) -> R2 bf16
    gemm_kernel<1><<<256, 1024, 0, stream>>>(Rs, WTb, (void*)R2, Ux, b_odd);
    // GEMM2: out = R2 @ W^T (+b_even) -> d_out f32
    gemm_kernel<2><<<256, 1024, 0, stream>>>(R2, Wb, d_out, Ux, b_even);
}